// Round 6
// baseline (113.803 us; speedup 1.0000x reference)
//
#include <hip/hip_runtime.h>
#include <math.h>

#define Bn  16
#define Hn  384
#define Wn  512
#define HWn (Hn * Wn)

typedef float f4 __attribute__((ext_vector_type(4)));

// 1536 blocks x 256 threads. Block = 4 waves; wave = one image row
// (64 lanes x 8 px, u = j*64 + lane -> lane-contiguous loads/stores).
// Block index swizzled so XCD n%8 owns a band of 48 consecutive rows per
// batch (gather-row reuse in one L2).
// Gather: per row-pair, 2 aligned dwordx4 + 1 dword (instead of 6 scattered
// dwords) + branchless cndmask extraction -> halves L1 scattered-line work.
// Output staged through wave-private LDS -> 6 fully-covered 1KiB stores/row.
__global__ __launch_bounds__(256) void ProjectionLayer_678604833211_kernel(
    const float* __restrict__ src,    // [B,H,W,3]
    const float* __restrict__ depth,  // [B,H,W]
    const float* __restrict__ pose,   // [B,6]
    const float* __restrict__ intr,   // [3,3]
    float* __restrict__ out)          // [B,H,W,3]
{
    __shared__ float S[16];
    __shared__ float rowbuf[4][Wn * 3];   // 24 KiB, one 6144B slice per wave

    const int n    = blockIdx.x;
    const int xcd  = n & 7;
    const int m    = n >> 3;            // [0,192)
    const int b    = m / 12;            // batch
    const int sub  = m - b * 12;
    const int rowblk = xcd * 12 + sub;  // [0,96) within batch

    const int wave = threadIdx.x >> 6;
    const int lane = threadIdx.x & 63;
    const int row  = rowblk * 4 + wave;

    const size_t rowpx = (size_t)b * HWn + (size_t)row * Wn;
    const float* __restrict__ drow = depth + rowpx;

    // Depth loads FIRST — latency overlaps pose math + barrier.
    float dv[8];
    #pragma unroll
    for (int j = 0; j < 8; ++j)
        dv[j] = drow[j * 64 + lane];

    if (threadIdx.x == 0) {
        const float fx = intr[0], cx = intr[2], fy = intr[4], cy = intr[5];
        const float tx = pose[b * 6 + 0] * 0.01f;
        const float ty = pose[b * 6 + 1] * 0.01f;
        const float tz = pose[b * 6 + 2] * 0.01f;
        const float rx = pose[b * 6 + 3] * 0.001f;
        const float ry = pose[b * 6 + 4] * 0.001f;
        const float rz = pose[b * 6 + 5] * 0.001f;
        const float cX = cosf(rx), sX = sinf(rx);
        const float cY = cosf(ry), sY = sinf(ry);
        const float cZ = cosf(rz), sZ = sinf(rz);
        // R = (Rz @ Ry) @ Rx   (match reference associativity)
        const float R00 = cZ * cY;
        const float R01 = -sZ * cX + cZ * sY * sX;
        const float R02 =  sZ * sX + cZ * sY * cX;
        const float R10 = sZ * cY;
        const float R11 =  cZ * cX + sZ * sY * sX;
        const float R12 = -cZ * sX + sZ * sY * cX;
        const float R20 = -sY;
        const float R21 = cY * sX;
        const float R22 = cY * cX;
        S[0]  = fx * R00 + cx * R20;
        S[1]  = fx * R01 + cx * R21;
        S[2]  = fx * R02 + cx * R22;
        S[3]  = fx * tx  + cx * tz;
        S[4]  = fy * R10 + cy * R20;
        S[5]  = fy * R11 + cy * R21;
        S[6]  = fy * R12 + cy * R22;
        S[7]  = fy * ty  + cy * tz;
        S[8]  = R20;
        S[9]  = R21;
        S[10] = R22;
        S[11] = tz;
        S[12] = 1.0f / fx;
        S[13] = -cx / fx;
        S[14] = 1.0f / fy;
        S[15] = -cy / fy;
    }
    __syncthreads();

    const float m0 = S[0],  m1 = S[1],  m2  = S[2],  m3  = S[3];
    const float m4 = S[4],  m5 = S[5],  m6  = S[6],  m7  = S[7];
    const float m8 = S[8],  m9 = S[9],  m10 = S[10], m11 = S[11];
    const float ifx = S[12], nfx = S[13], ify = S[14], nfy = S[15];

    const float camy_u = fmaf((float)row, ify, nfy);  // camy per unit depth
    const float* __restrict__ base = src + (size_t)b * HWn * 3;
    float* __restrict__ wbuf = &rowbuf[wave][0];

    #pragma unroll
    for (int j = 0; j < 8; ++j) {
        const int   u = j * 64 + lane;
        const float d = dv[j];
        const float camx = fmaf((float)u, ifx, nfx) * d;
        const float camy = camy_u * d;

        const float p0 = fmaf(m0, camx, fmaf(m1, camy, fmaf(m2,  d, m3)));
        const float p1 = fmaf(m4, camx, fmaf(m5, camy, fmaf(m6,  d, m7)));
        const float p2 = fmaf(m8, camx, fmaf(m9, camy, fmaf(m10, d, m11)));

        const float inv = 1.0f / (p2 + 1e-10f);
        const float x = p0 * inv;
        const float y = p1 * inv;

        const float x0f = floorf(x), y0f = floorf(y);
        const float ax = x - x0f;
        const float ay = y - y0f;
        const float bx = (x0f + 1.0f) - x;   // match reference rounding
        const float by = (y0f + 1.0f) - y;

        const int x0 = (int)fminf(fmaxf(x0f,        0.0f), 511.0f);
        const int x1 = (int)fminf(fmaxf(x0f + 1.0f, 0.0f), 511.0f);
        const int p  = (int)fminf(fmaxf(x0f,        0.0f), 510.0f);
        const int y0 = (int)fminf(fmaxf(y0f,        0.0f), 383.0f);
        const int y1 = (int)fminf(fmaxf(y0f + 1.0f, 0.0f), 383.0f);

        // Fold border clamp into x-weights (branchless).
        const bool loA = (x0 == p);
        const bool hiC = (x1 == p + 1);
        const float xl = (loA ? bx : 0.0f) + (hiC ? 0.0f : ax);
        const float xh = (loA ? 0.0f : bx) + (hiC ? ax : 0.0f);

        // Wide-load gather: floats af..af+5 (pixels p, p+1) of each row.
        // af..af+4 come from the 16B-aligned 32B window [af&~3, af&~3+8);
        // af+5 loaded directly. p<=510 guarantees the window is in-bounds.
        const int af0 = (y0 * Wn + p) * 3;
        const int af1 = (y1 * Wn + p) * 3;

        const f4 qa0 = *(const f4*)(base + (af0 & ~3));
        const f4 qa1 = *(const f4*)(base + (af0 & ~3) + 4);
        const float ta5 = base[af0 + 5];
        const f4 qb0 = *(const f4*)(base + (af1 & ~3));
        const f4 qb1 = *(const f4*)(base + (af1 & ~3) + 4);
        const float tb5 = base[af1 + 5];

        float t0[6], t1[6];
        {
            const int k = af0 & 3;
            const bool k2 = (k & 2) != 0, k1 = (k & 1) != 0;
            const float A0 = k2 ? qa0.z : qa0.x;
            const float A1 = k2 ? qa0.w : qa0.y;
            const float A2 = k2 ? qa1.x : qa0.z;
            const float A3 = k2 ? qa1.y : qa0.w;
            const float B0 = k2 ? qa1.z : qa1.x;
            const float B1 = k2 ? qa1.w : qa1.y;
            t0[0] = k1 ? A1 : A0;
            t0[1] = k1 ? A2 : A1;
            t0[2] = k1 ? A3 : A2;
            t0[3] = k1 ? B0 : A3;
            t0[4] = k1 ? B1 : B0;
            t0[5] = ta5;
        }
        {
            const int k = af1 & 3;
            const bool k2 = (k & 2) != 0, k1 = (k & 1) != 0;
            const float A0 = k2 ? qb0.z : qb0.x;
            const float A1 = k2 ? qb0.w : qb0.y;
            const float A2 = k2 ? qb1.x : qb0.z;
            const float A3 = k2 ? qb1.y : qb0.w;
            const float B0 = k2 ? qb1.z : qb1.x;
            const float B1 = k2 ? qb1.w : qb1.y;
            t1[0] = k1 ? A1 : A0;
            t1[1] = k1 ? A2 : A1;
            t1[2] = k1 ? A3 : A2;
            t1[3] = k1 ? B0 : A3;
            t1[4] = k1 ? B1 : B0;
            t1[5] = tb5;
        }

        const float o0 = fmaf(by, fmaf(xl, t0[0], xh * t0[3]),
                              ay * fmaf(xl, t1[0], xh * t1[3]));
        const float o1 = fmaf(by, fmaf(xl, t0[1], xh * t0[4]),
                              ay * fmaf(xl, t1[1], xh * t1[4]));
        const float o2 = fmaf(by, fmaf(xl, t0[2], xh * t0[5]),
                              ay * fmaf(xl, t1[2], xh * t1[5]));

        // LDS stage: word addr 3*(j*64+lane)+c -> bank (3*lane+c)%32,
        // gcd(3,32)=1 -> conflict-free.
        wbuf[u * 3 + 0] = o0;
        wbuf[u * 3 + 1] = o1;
        wbuf[u * 3 + 2] = o2;
    }

    // Wave-private readback (no barrier needed): 6 x 1KiB fully-covered
    // contiguous NT stores per row.
    float* __restrict__ orow = out + rowpx * 3;
    #pragma unroll
    for (int k = 0; k < 6; ++k) {
        f4 v = *(const f4*)&wbuf[k * 256 + lane * 4];
        __builtin_nontemporal_store(v, (f4*)(orow + k * 256 + lane * 4));
    }
}

extern "C" void kernel_launch(void* const* d_in, const int* in_sizes, int n_in,
                              void* d_out, int out_size, void* d_ws, size_t ws_size,
                              hipStream_t stream) {
    const float* src   = (const float*)d_in[0];  // [16,384,512,3]
    const float* depth = (const float*)d_in[1];  // [16,384,512]
    const float* pose  = (const float*)d_in[2];  // [16,6]
    const float* intr  = (const float*)d_in[3];  // [3,3]
    float* out = (float*)d_out;

    dim3 grid(Bn * 96);   // 16 batches x 96 row-blocks (XCD-swizzled)
    dim3 block(256);
    ProjectionLayer_678604833211_kernel<<<grid, block, 0, stream>>>(
        src, depth, pose, intr, out);
}

// Round 8
// 105.163 us; speedup vs baseline: 1.0822x; 1.0822x over previous
//
#include <hip/hip_runtime.h>
#include <hip/hip_fp16.h>
#include <math.h>

#define Bn  16
#define Hn  384
#define Wn  512
#define HWn (Hn * Wn)
#define SRC16_BYTES ((size_t)Bn * HWn * 3 * 2)   // 18,874,368 B in d_ws

typedef float    f4 __attribute__((ext_vector_type(4)));
typedef unsigned u4 __attribute__((ext_vector_type(4)));

__device__ __forceinline__ unsigned pack2(float a, float b) {
    __half2 h = __floats2half2_rn(a, b);
    unsigned r;
    __builtin_memcpy(&r, &h, 4);
    return r;
}

// ---------------- prepass: fp32 interleaved -> fp16 interleaved -------------
// 9,437,184 floats, 8 per thread -> 4608 blocks x 256. Pure streaming.
__global__ __launch_bounds__(256) void ProjectionLayer_cvt16_kernel(
    const float* __restrict__ src, unsigned short* __restrict__ dst)
{
    const size_t i = ((size_t)blockIdx.x * 256 + threadIdx.x) * 8;
    const f4 a = *(const f4*)(src + i);
    const f4 c = *(const f4*)(src + i + 4);
    u4 q = {pack2(a.x, a.y), pack2(a.z, a.w), pack2(c.x, c.y), pack2(c.z, c.w)};
    *(u4*)(dst + i) = q;   // byte offset 2*i, i%8==0 -> 16B aligned
}

// Shared pose/projection setup (thread 0 of each block).
__device__ __forceinline__ void setup_S(float* S, const float* pose,
                                        const float* intr, int b)
{
    const float fx = intr[0], cx = intr[2], fy = intr[4], cy = intr[5];
    const float tx = pose[b * 6 + 0] * 0.01f;
    const float ty = pose[b * 6 + 1] * 0.01f;
    const float tz = pose[b * 6 + 2] * 0.01f;
    const float rx = pose[b * 6 + 3] * 0.001f;
    const float ry = pose[b * 6 + 4] * 0.001f;
    const float rz = pose[b * 6 + 5] * 0.001f;
    const float cX = cosf(rx), sX = sinf(rx);
    const float cY = cosf(ry), sY = sinf(ry);
    const float cZ = cosf(rz), sZ = sinf(rz);
    // R = (Rz @ Ry) @ Rx   (match reference associativity)
    const float R00 = cZ * cY;
    const float R01 = -sZ * cX + cZ * sY * sX;
    const float R02 =  sZ * sX + cZ * sY * cX;
    const float R10 = sZ * cY;
    const float R11 =  cZ * cX + sZ * sY * sX;
    const float R12 = -cZ * sX + sZ * sY * cX;
    const float R20 = -sY;
    const float R21 = cY * sX;
    const float R22 = cY * cX;
    S[0]  = fx * R00 + cx * R20;
    S[1]  = fx * R01 + cx * R21;
    S[2]  = fx * R02 + cx * R22;
    S[3]  = fx * tx  + cx * tz;
    S[4]  = fy * R10 + cy * R20;
    S[5]  = fy * R11 + cy * R21;
    S[6]  = fy * R12 + cy * R22;
    S[7]  = fy * ty  + cy * tz;
    S[8]  = R20;
    S[9]  = R21;
    S[10] = R22;
    S[11] = tz;
    S[12] = 1.0f / fx;
    S[13] = -cx / fx;
    S[14] = 1.0f / fy;
    S[15] = -cy / fy;
}

// ---------------- main: project + gather(fp16) + LDS-staged stores ----------
// 1536 blocks x 256. Block = 4 waves; wave = one image row (u = j*64+lane).
// XCD band swizzle: XCD n%8 owns 48 consecutive rows/batch (L2 reuse).
// Gather: ONE dword-aligned dwordx4 per (pixel,row) covers the whole 12B
// fp16 row-segment; extraction = alignbit/cndmask + half2->float2 (VALU idle).
__global__ __launch_bounds__(256) void ProjectionLayer_678604833211_kernel(
    const unsigned* __restrict__ srcu,  // fp16 interleaved [B,H,W,3] in ws
    const float* __restrict__ depth,    // [B,H,W]
    const float* __restrict__ pose,     // [B,6]
    const float* __restrict__ intr,     // [3,3]
    float* __restrict__ out)            // [B,H,W,3]
{
    __shared__ float S[16];
    __shared__ float rowbuf[4][Wn * 3];   // 24 KiB, one 6144B slice per wave

    const int n    = blockIdx.x;
    const int xcd  = n & 7;
    const int m    = n >> 3;            // [0,192)
    const int b    = m / 12;            // batch
    const int sub  = m - b * 12;
    const int rowblk = xcd * 12 + sub;  // [0,96) within batch

    const int wave = threadIdx.x >> 6;
    const int lane = threadIdx.x & 63;
    const int row  = rowblk * 4 + wave;

    const size_t rowpx = (size_t)b * HWn + (size_t)row * Wn;
    const float* __restrict__ drow = depth + rowpx;

    // Depth loads first — latency overlaps pose math + barrier.
    float dv[8];
    #pragma unroll
    for (int j = 0; j < 8; ++j)
        dv[j] = drow[j * 64 + lane];

    if (threadIdx.x == 0) setup_S(S, pose, intr, b);
    __syncthreads();

    const float m0 = S[0],  m1 = S[1],  m2  = S[2],  m3  = S[3];
    const float m4 = S[4],  m5 = S[5],  m6  = S[6],  m7  = S[7];
    const float m8 = S[8],  m9 = S[9],  m10 = S[10], m11 = S[11];
    const float ifx = S[12], nfx = S[13], ify = S[14], nfy = S[15];

    const float camy_u = fmaf((float)row, ify, nfy);
    const unsigned* __restrict__ basep = srcu + (size_t)b * (HWn * 3 / 2);
    float* __restrict__ wbuf = &rowbuf[wave][0];

    #pragma unroll
    for (int j = 0; j < 8; ++j) {
        const int   u = j * 64 + lane;
        const float d = dv[j];
        const float camx = fmaf((float)u, ifx, nfx) * d;
        const float camy = camy_u * d;

        const float p0 = fmaf(m0, camx, fmaf(m1, camy, fmaf(m2,  d, m3)));
        const float p1 = fmaf(m4, camx, fmaf(m5, camy, fmaf(m6,  d, m7)));
        const float p2 = fmaf(m8, camx, fmaf(m9, camy, fmaf(m10, d, m11)));

        const float inv = 1.0f / (p2 + 1e-10f);
        const float x = p0 * inv;
        const float y = p1 * inv;

        const float x0f = floorf(x), y0f = floorf(y);
        const float ax = x - x0f;
        const float ay = y - y0f;
        const float bx = (x0f + 1.0f) - x;   // match reference rounding
        const float by = (y0f + 1.0f) - y;

        const int x0 = (int)fminf(fmaxf(x0f,        0.0f), 511.0f);
        const int x1 = (int)fminf(fmaxf(x0f + 1.0f, 0.0f), 511.0f);
        const int p  = (int)fminf(fmaxf(x0f,        0.0f), 510.0f);
        const int y0 = (int)fminf(fmaxf(y0f,        0.0f), 383.0f);
        const int y1 = (int)fminf(fmaxf(y0f + 1.0f, 0.0f), 383.0f);

        // Fold border clamp into x-weights (branchless).
        const bool loA = (x0 == p);
        const bool hiC = (x1 == p + 1);
        const float xl = (loA ? bx : 0.0f) + (hiC ? 0.0f : ax);
        const float xh = (loA ? 0.0f : bx) + (hiC ? ax : 0.0f);

        // fp16 gather: row segment = 6 halfs (12B) at byte 6p; 6p%4 in {0,2},
        // so the 16B window at uint index (3p)>>1 always covers it.
        // Row stride = 768 uints. p<=510 keeps the needed 12B in-bounds.
        const int ci = (3 * p) >> 1;
        unsigned qa[4], qb[4];
        __builtin_memcpy(qa, basep + y0 * 768 + ci, 16);
        __builtin_memcpy(qb, basep + y1 * 768 + ci, 16);

        const bool odd = (p & 1) != 0;
        unsigned Ea0 = odd ? __builtin_amdgcn_alignbit(qa[1], qa[0], 16) : qa[0];
        unsigned Ea1 = odd ? __builtin_amdgcn_alignbit(qa[2], qa[1], 16) : qa[1];
        unsigned Ea2 = odd ? __builtin_amdgcn_alignbit(qa[3], qa[2], 16) : qa[2];
        unsigned Eb0 = odd ? __builtin_amdgcn_alignbit(qb[1], qb[0], 16) : qb[0];
        unsigned Eb1 = odd ? __builtin_amdgcn_alignbit(qb[2], qb[1], 16) : qb[1];
        unsigned Eb2 = odd ? __builtin_amdgcn_alignbit(qb[3], qb[2], 16) : qb[2];

        __half2 ha0, ha1, ha2, hb0, hb1, hb2;
        __builtin_memcpy(&ha0, &Ea0, 4);
        __builtin_memcpy(&ha1, &Ea1, 4);
        __builtin_memcpy(&ha2, &Ea2, 4);
        __builtin_memcpy(&hb0, &Eb0, 4);
        __builtin_memcpy(&hb1, &Eb1, 4);
        __builtin_memcpy(&hb2, &Eb2, 4);
        const float2 Fa0 = __half22float2(ha0);  // (c0@p,   c1@p)   row y0
        const float2 Fa1 = __half22float2(ha1);  // (c2@p,   c0@p+1)
        const float2 Fa2 = __half22float2(ha2);  // (c1@p+1, c2@p+1)
        const float2 Fb0 = __half22float2(hb0);  // same, row y1
        const float2 Fb1 = __half22float2(hb1);
        const float2 Fb2 = __half22float2(hb2);

        const float o0 = fmaf(by, fmaf(xl, Fa0.x, xh * Fa1.y),
                              ay * fmaf(xl, Fb0.x, xh * Fb1.y));
        const float o1 = fmaf(by, fmaf(xl, Fa0.y, xh * Fa2.x),
                              ay * fmaf(xl, Fb0.y, xh * Fb2.x));
        const float o2 = fmaf(by, fmaf(xl, Fa1.x, xh * Fa2.y),
                              ay * fmaf(xl, Fb1.x, xh * Fb2.y));

        // LDS stage: word addr 3u+c -> bank (3*lane+c)%32, conflict-free.
        wbuf[u * 3 + 0] = o0;
        wbuf[u * 3 + 1] = o1;
        wbuf[u * 3 + 2] = o2;
    }

    // Wave-private readback: 6 x 1KiB fully-covered contiguous NT stores.
    float* __restrict__ orow = out + rowpx * 3;
    #pragma unroll
    for (int k = 0; k < 6; ++k) {
        f4 v = *(const f4*)&wbuf[k * 256 + lane * 4];
        __builtin_nontemporal_store(v, (f4*)(orow + k * 256 + lane * 4));
    }
}

// ---------------- fallback (R4 fp32 path) if ws too small -------------------
__global__ __launch_bounds__(256) void ProjectionLayer_fp32_kernel(
    const float* __restrict__ src, const float* __restrict__ depth,
    const float* __restrict__ pose, const float* __restrict__ intr,
    float* __restrict__ out)
{
    __shared__ float S[16];
    __shared__ float rowbuf[4][Wn * 3];

    const int n    = blockIdx.x;
    const int xcd  = n & 7;
    const int m    = n >> 3;
    const int b    = m / 12;
    const int sub  = m - b * 12;
    const int rowblk = xcd * 12 + sub;

    const int wave = threadIdx.x >> 6;
    const int lane = threadIdx.x & 63;
    const int row  = rowblk * 4 + wave;

    const size_t rowpx = (size_t)b * HWn + (size_t)row * Wn;
    const float* __restrict__ drow = depth + rowpx;

    float dv[8];
    #pragma unroll
    for (int j = 0; j < 8; ++j)
        dv[j] = drow[j * 64 + lane];

    if (threadIdx.x == 0) setup_S(S, pose, intr, b);
    __syncthreads();

    const float m0 = S[0],  m1 = S[1],  m2  = S[2],  m3  = S[3];
    const float m4 = S[4],  m5 = S[5],  m6  = S[6],  m7  = S[7];
    const float m8 = S[8],  m9 = S[9],  m10 = S[10], m11 = S[11];
    const float ifx = S[12], nfx = S[13], ify = S[14], nfy = S[15];

    const float camy_u = fmaf((float)row, ify, nfy);
    const float* __restrict__ base = src + (size_t)b * HWn * 3;
    float* __restrict__ wbuf = &rowbuf[wave][0];

    #pragma unroll
    for (int j = 0; j < 8; ++j) {
        const int   u = j * 64 + lane;
        const float d = dv[j];
        const float camx = fmaf((float)u, ifx, nfx) * d;
        const float camy = camy_u * d;
        const float p0 = fmaf(m0, camx, fmaf(m1, camy, fmaf(m2,  d, m3)));
        const float p1 = fmaf(m4, camx, fmaf(m5, camy, fmaf(m6,  d, m7)));
        const float p2 = fmaf(m8, camx, fmaf(m9, camy, fmaf(m10, d, m11)));
        const float inv = 1.0f / (p2 + 1e-10f);
        const float x = p0 * inv;
        const float y = p1 * inv;

        const float x0f = floorf(x), y0f = floorf(y);
        const float ax = x - x0f, ay = y - y0f;
        const float bx = (x0f + 1.0f) - x, by = (y0f + 1.0f) - y;

        const int x0 = (int)fminf(fmaxf(x0f,        0.0f), 511.0f);
        const int x1 = (int)fminf(fmaxf(x0f + 1.0f, 0.0f), 511.0f);
        const int p  = (int)fminf(fmaxf(x0f,        0.0f), 510.0f);
        const int y0 = (int)fminf(fmaxf(y0f,        0.0f), 383.0f);
        const int y1 = (int)fminf(fmaxf(y0f + 1.0f, 0.0f), 383.0f);

        const bool loA = (x0 == p);
        const bool hiC = (x1 == p + 1);
        const float xl = (loA ? bx : 0.0f) + (hiC ? 0.0f : ax);
        const float xh = (loA ? 0.0f : bx) + (hiC ? ax : 0.0f);

        float t0[6], t1[6];
        __builtin_memcpy(t0, base + (size_t)(y0 * Wn + p) * 3, 24);
        __builtin_memcpy(t1, base + (size_t)(y1 * Wn + p) * 3, 24);

        wbuf[u * 3 + 0] = fmaf(by, fmaf(xl, t0[0], xh * t0[3]),
                               ay * fmaf(xl, t1[0], xh * t1[3]));
        wbuf[u * 3 + 1] = fmaf(by, fmaf(xl, t0[1], xh * t0[4]),
                               ay * fmaf(xl, t1[1], xh * t1[4]));
        wbuf[u * 3 + 2] = fmaf(by, fmaf(xl, t0[2], xh * t0[5]),
                               ay * fmaf(xl, t1[2], xh * t1[5]));
    }

    float* __restrict__ orow = out + rowpx * 3;
    #pragma unroll
    for (int k = 0; k < 6; ++k) {
        f4 v = *(const f4*)&wbuf[k * 256 + lane * 4];
        __builtin_nontemporal_store(v, (f4*)(orow + k * 256 + lane * 4));
    }
}

extern "C" void kernel_launch(void* const* d_in, const int* in_sizes, int n_in,
                              void* d_out, int out_size, void* d_ws, size_t ws_size,
                              hipStream_t stream) {
    const float* src   = (const float*)d_in[0];  // [16,384,512,3]
    const float* depth = (const float*)d_in[1];  // [16,384,512]
    const float* pose  = (const float*)d_in[2];  // [16,6]
    const float* intr  = (const float*)d_in[3];  // [3,3]
    float* out = (float*)d_out;

    if (ws_size >= SRC16_BYTES + 16) {
        unsigned short* src16 = (unsigned short*)d_ws;
        ProjectionLayer_cvt16_kernel<<<dim3(Bn * HWn * 3 / (256 * 8)), dim3(256),
                                       0, stream>>>(src, src16);
        ProjectionLayer_678604833211_kernel<<<dim3(Bn * 96), dim3(256), 0, stream>>>(
            (const unsigned*)src16, depth, pose, intr, out);
    } else {
        ProjectionLayer_fp32_kernel<<<dim3(Bn * 96), dim3(256), 0, stream>>>(
            src, depth, pose, intr, out);
    }
}